// Round 10
// baseline (85.136 us; speedup 1.0000x reference)
//
#include <hip/hip_runtime.h>

// ElementalGTOLogNormalSkinCutoff on MI355X (gfx950) — FINAL (round-5 lock-in)
//
// Two-phase: phase 1 computes per-neighbour shared quantities once and
// bucket-sorts neighbours by species into LDS; phase 2 (thread = atom,g)
// runs 4 branch-free species-segment loops with static T[s][a] indexing.
//
// Session summary (rounds 1-9):
//  * R1 naive (atom,g)-thread: 57 us kernel — 20x redundant per-neighbour
//    work + 4x select-FMA waste.
//  * R2 two-phase + species sort: REGRESSED (dyn-indexed record arrays ->
//    scratch spill, VALUBusy 0.6%; LDS row stride = 0 mod 32 banks -> 451k
//    bank conflicts). R3 fixed both (static unroll + row pad): best-so-far.
//  * R4 Horner-in-exp2 radial fold: NaN from log2(negative cut) at d~6
//    boundary (GPU rsqrt ~2ulp vs numpy float64 neighbour selection).
//    R5 = R4 + amp clamp to 1e-30: 84.1 us bench — BEST MEASURED.
//  * R6 (g-pairs, half the LDS reads), R7 (16B fp16-packed records),
//    R8 (pad-to-4 + x4 unroll), R9 (wave-ballot single-pass phase 1,
//    1 barrier): all within noise (84-88) — phase-2 LDS reads are
//    same-address broadcasts across an atom's 20 g-lanes, so none of the
//    theorized LDS/overhead bottlenecks were real. Residual kernel time is
//    latency exposure + launch overhead; bench is dominated by ~64 us of
//    harness re-poison/restore (268 MB fill ~44 us each).
//
// Record: P=(c0,c1,c2,ux), Q=(uy,uz); rad = exp2(c0*lo^2 + c1*lo + c2),
// c0=-0.5*log2e/sigma2, c1=-2*c0*mu, c2=c0*mu^2+log2(amp),
// amp = rsqrt(sigma2)*cut/d^2 clamped to 1e-30 (cut can be ~-1e-7 at d~6).

#define B_   128
#define N_   128
#define M_   64
#define NG_  20
#define NSP_ 4
#define FPSIZE_ 600
#define APB  16                     // atoms per block (divides N_, so b uniform)
#define NTASK (APB * M_)            // 1024 neighbour slots per block
#define BLOCK_THREADS (APB * NG_)   // 320 = 5 waves
#define P1ITER 4                    // ceil(1024/320)

__global__ __launch_bounds__(BLOCK_THREADS)
void gto_fp_kernel(const float* __restrict__ coords,   // [B,N,3]
                   const int*   __restrict__ charges,  // [B,N]
                   const int*   __restrict__ counts,   // [B]
                   const int*   __restrict__ neigh,    // [B,N,M]
                   float*       __restrict__ out)      // [B,N,600]
{
    __shared__ float4 sP[APB][M_ + 1];      // c0, c1, c2, ux  (padded row)
    __shared__ float2 sQ[APB][M_ + 1];      // uy, uz          (padded row)
    __shared__ int s_cnt[APB][NSP_];
    __shared__ int s_start[APB][NSP_];
    __shared__ int s_pos[APB][NSP_];

    const int tid = threadIdx.x;
    const int blockBase = blockIdx.x * APB;
    const int bidx = blockBase / N_;        // uniform: APB divides N_

    if (tid < APB * NSP_) ((int*)s_cnt)[tid] = 0;
    __syncthreads();

    // ---------------- phase 1: build records + count (all static regs) ----
    float4 rP[P1ITER];
    float2 rQ[P1ITER];
    int    rls[P1ITER];
    bool   rv[P1ITER];

#pragma unroll
    for (int it = 0; it < P1ITER; ++it) {
        const int t = tid + it * BLOCK_THREADS;
        bool v = (t < NTASK);
        int la = 0, s = 0;
        float4 P = make_float4(0.f, 0.f, 0.f, 0.f);
        float2 Q = make_float2(0.f, 0.f);
        if (v) {
            la = t >> 6;
            const int m  = t & 63;
            const int atom = blockBase + la;
            const int nb = neigh[atom * M_ + m];
            if (nb < 0) {
                v = false;
            } else {
                const int nidx = bidx * N_ + nb;
                const float dx = coords[atom * 3 + 0] - coords[nidx * 3 + 0];
                const float dy = coords[atom * 3 + 1] - coords[nidx * 3 + 1];
                const float dz = coords[atom * 3 + 2] - coords[nidx * 3 + 2];
                const int   z  = charges[nidx];

                const float d2     = dx * dx + dy * dy + dz * dz;
                const float inv_d  = __builtin_amdgcn_rsqf(d2);
                const float d      = d2 * inv_d;
                const float inv_d2 = inv_d * inv_d;

                const float dsw  = (d - 1.0f) * 0.2f;
                const float dsw2 = dsw * dsw;
                const float cut  = 1.0f - dsw2 * dsw * fmaf(6.0f, dsw2, fmaf(-15.0f, dsw, 10.0f));

                const float sigma2 = __logf(fmaf(2.0f, inv_d2, 1.0f));     // log(1+W/d^2)
                const float mu     = 0.5f * (__logf(d2) - sigma2);         // log(d)-s2/2
                const float amp    = fmaxf(__builtin_amdgcn_rsqf(sigma2) * cut * inv_d2,
                                           1.0e-30f);   // clamp: cut can be ~-1e-7 at d~6

                const float F  = -0.72134752f * __builtin_amdgcn_rcpf(sigma2); // -0.5*log2e/s2
                const float Fm = F * mu;
                const float c0 = F;
                const float c1 = -(Fm + Fm);
                const float c2 = fmaf(Fm, mu, __log2f(amp));

                s = (z == 1) ? 0 : (z - 5);   // {1,6,7,8} -> {0,1,2,3}
                P = make_float4(c0, c1, c2, dx * inv_d);
                Q = make_float2(dy * inv_d, dz * inv_d);
                atomicAdd(&s_cnt[la][s], 1);
            }
        }
        rP[it] = P; rQ[it] = Q; rls[it] = (la << 2) | s; rv[it] = v;
    }
    __syncthreads();

    if (tid < APB) {
        const int c0 = s_cnt[tid][0], c1 = s_cnt[tid][1], c2 = s_cnt[tid][2];
        s_start[tid][0] = 0;            s_pos[tid][0] = 0;
        s_start[tid][1] = c0;           s_pos[tid][1] = c0;
        s_start[tid][2] = c0 + c1;      s_pos[tid][2] = c0 + c1;
        s_start[tid][3] = c0 + c1 + c2; s_pos[tid][3] = c0 + c1 + c2;
    }
    __syncthreads();

#pragma unroll
    for (int it = 0; it < P1ITER; ++it) {
        if (rv[it]) {
            const int la = rls[it] >> 2, s = rls[it] & 3;
            const int slot = atomicAdd(&s_pos[la][s], 1);
            sP[la][slot] = rP[it];
            sQ[la][slot] = rQ[it];
        }
    }
    __syncthreads();

    // ---------------- phase 2: accumulate T, emit outputs ----------------
    const int g  = tid % NG_;
    const int la = tid / NG_;
    const int atom = blockBase + la;
    const int n = atom % N_;

    const float off         = 0.3f * (float)(g + 1);
    const float lo          = __logf(off);            // natural-log space
    const float lo2         = lo * lo;
    const float inv_off_spi = 1.0f / (off * 1.7724538509055159f);

    float T[NSP_][10];
#pragma unroll
    for (int s = 0; s < NSP_; ++s)
#pragma unroll
        for (int a = 0; a < 10; ++a) T[s][a] = 0.0f;

#define BODY(SS, P, Q)                                                        \
    {                                                                         \
        const float rad = __builtin_amdgcn_exp2f(                             \
            fmaf(P.x, lo2, fmaf(P.y, lo, P.z)));                              \
        const float rx = rad * P.w, ry = rad * Q.x, rz = rad * Q.y;           \
        T[SS][0] += rad;                                                      \
        T[SS][1] += rx;  T[SS][2] += ry;  T[SS][3] += rz;                     \
        T[SS][4] = fmaf(rx, P.w, T[SS][4]);                                   \
        T[SS][5] = fmaf(rx, Q.x, T[SS][5]);                                   \
        T[SS][6] = fmaf(ry, Q.x, T[SS][6]);                                   \
        T[SS][7] = fmaf(rx, Q.y, T[SS][7]);                                   \
        T[SS][8] = fmaf(ry, Q.y, T[SS][8]);                                   \
        T[SS][9] = fmaf(rz, Q.y, T[SS][9]);                                   \
    }

#define ACC(SS)                                                               \
    {                                                                         \
        const int e0 = s_start[la][SS];                                       \
        const int e1 = e0 + s_cnt[la][SS];                                    \
        int m = e0;                                                           \
        for (; m + 1 < e1; m += 2) {                                          \
            const float4 Pa = sP[la][m];     const float2 Qa = sQ[la][m];     \
            const float4 Pb = sP[la][m + 1]; const float2 Qb = sQ[la][m + 1]; \
            BODY(SS, Pa, Qa)                                                  \
            BODY(SS, Pb, Qb)                                                  \
        }                                                                     \
        if (m < e1) {                                                         \
            const float4 Pa = sP[la][m]; const float2 Qa = sQ[la][m];         \
            BODY(SS, Pa, Qa)                                                  \
        }                                                                     \
    }
    ACC(0) ACC(1) ACC(2) ACC(3)
#undef ACC
#undef BODY

    // output scale: atom mask * (1/(off*sqrt(pi)))^2  (quadratic in T)
    const float amask = (n < counts[bidx]) ? 1.0f : 0.0f;
    const float scale = amask * inv_off_spi * inv_off_spi;
    float* op = out + atom * FPSIZE_ + g;

    // angw = [1, 1,1,1, 1,2,1,2,2,1]; lw = 1 for all l
#pragma unroll
    for (int l = 0; l < 3; ++l) {
        const int a0 = (l == 0) ? 0 : (l == 1) ? 1 : 4;
        const int a1 = (l == 0) ? 1 : (l == 1) ? 4 : 10;
#pragma unroll
        for (int s = 0; s < NSP_; ++s) {
            float v = 0.0f;
#pragma unroll
            for (int a = a0; a < a1; ++a) {
                const float w = (a == 5 || a == 7 || a == 8) ? 2.0f : 1.0f;
                v = fmaf(w * T[s][a], T[s][a], v);
            }
            op[(l * 10 + s) * NG_] = scale * v;
        }
        int mb = 4;
#pragma unroll
        for (int i = 0; i < NSP_; ++i) {
#pragma unroll
            for (int j = i + 1; j < NSP_; ++j) {
                float v = 0.0f;
#pragma unroll
                for (int a = a0; a < a1; ++a) {
                    const float w = (a == 5 || a == 7 || a == 8) ? 2.0f : 1.0f;
                    v = fmaf(w * T[i][a], T[j][a], v);
                }
                op[(l * 10 + mb) * NG_] = scale * (2.0f * v);
                ++mb;
            }
        }
    }
}

extern "C" void kernel_launch(void* const* d_in, const int* in_sizes, int n_in,
                              void* d_out, int out_size, void* d_ws, size_t ws_size,
                              hipStream_t stream) {
    const float* coords  = (const float*)d_in[0];
    const int*   charges = (const int*)d_in[1];
    const int*   counts  = (const int*)d_in[2];
    const int*   neigh   = (const int*)d_in[3];
    float*       outp    = (float*)d_out;

    const int blocks = (B_ * N_) / APB;   // 1024
    gto_fp_kernel<<<blocks, BLOCK_THREADS, 0, stream>>>(coords, charges, counts, neigh, outp);
}